// Round 2
// baseline (506.880 us; speedup 1.0000x reference)
//
#include <hip/hip_runtime.h>

#define Bdim 8
#define Cdim 64
#define Ndim 4096
#define Kdim 32
#define ROWS (Bdim*Ndim)   /* 32768 */
#define BN_EPS 1e-5f

using f32x4  = __attribute__((ext_vector_type(4))) float;
using bf16x8 = __attribute__((ext_vector_type(8))) short;

__device__ __forceinline__ float dot4(float4 a, float4 b){
  return a.x*b.x + a.y*b.y + a.z*b.z + a.w*b.w;
}
__device__ __forceinline__ int wofs(int o, int g){ return o*64 + (((g ^ ((o>>2)&7)))<<2); }
__device__ __forceinline__ unsigned keyOf(float f){
  unsigned u = __float_as_uint(f);
  return (u & 0x80000000u) ? ~u : (u ^ 0x80000000u);
}

// ---------------------------------------------------------------- prep+proj fused
__global__ __launch_bounds__(256) void prep_proj_kernel(const float* __restrict__ x,
    const float* __restrict__ wq, const float* __restrict__ wk,
    const float* __restrict__ wv,
    float* __restrict__ sq,
    float* __restrict__ Qo, float* __restrict__ PKo, float* __restrict__ PVo,
    float* __restrict__ accZ,
    float* __restrict__ featT, unsigned short* __restrict__ xh)
{
  __shared__ __align__(16) float ftile[64*68];
  __shared__ __align__(16) float Ws[3][64*64];
  const int tid = threadIdx.x;
  const int blk = blockIdx.x;
  const int b  = blk & 7;
  const int n0 = (blk >> 3) * 64;
  const size_t rowBase = (size_t)b*Ndim + n0;
  if (blk == 0) accZ[tid] = 0.f;   // 256 floats: bn1s, bn1q, bn2s, bn2q
  for (int k=0;k<16;++k){
    int idx = tid + (k<<8);
    int c = idx>>6, nn = idx&63;
    ftile[nn*68+c] = x[((size_t)b*64+c)*Ndim + n0 + nn];
  }
  {
    const float* wp[3] = {wq, wk, wv};
    for (int m=0;m<3;++m)
      for (int k=0;k<16;++k){
        int idx = tid + (k<<8);
        int o = idx>>6, c = idx&63;
        Ws[m][wofs(o, c>>2) + (c&3)] = wp[m][o*64 + c];
      }
  }
  __syncthreads();
  // featT (fp32) + xh (bf16 RTNE) writes, coalesced
  for (int k=0;k<16;++k){
    int idx = tid + (k<<8);
    int r = idx>>6, c = idx&63;
    float v = ftile[r*68+c];
    size_t o = (rowBase + r)*64 + c;
    featT[o] = v;
    unsigned u = __float_as_uint(v);
    xh[o] = (unsigned short)((u + 0x7FFFu + ((u>>16)&1u)) >> 16);
  }
  if (tid < 64){
    float a = 0.f;
    #pragma unroll
    for (int c=0;c<64;++c){ float v = ftile[tid*68+c]; a += v*v; }
    sq[b*Ndim + n0 + tid] = a;
  }
  const int tr = tid>>4, to = tid&15;
  float* outp[3] = {Qo, PKo, PVo};
  for (int m=0;m<3;++m){
    float acc[4][4];
    #pragma unroll
    for (int r=0;r<4;++r){ acc[r][0]=0.f; acc[r][1]=0.f; acc[r][2]=0.f; acc[r][3]=0.f; }
    #pragma unroll 4
    for (int c4=0;c4<16;++c4){
      float4 f[4], w[4];
      #pragma unroll
      for (int r=0;r<4;++r)  f[r] = *(const float4*)&ftile[(4*tr+r)*68 + (c4<<2)];
      #pragma unroll
      for (int oo=0;oo<4;++oo) w[oo] = *(const float4*)&Ws[m][wofs(4*to+oo, c4)];
      #pragma unroll
      for (int r=0;r<4;++r)
        #pragma unroll
        for (int oo=0;oo<4;++oo)
          acc[r][oo] += dot4(f[r], w[oo]);
    }
    #pragma unroll
    for (int r=0;r<4;++r){
      float4 v; v.x=acc[r][0]; v.y=acc[r][1]; v.z=acc[r][2]; v.w=acc[r][3];
      *(float4*)&outp[m][(rowBase + 4*tr + r)*64 + 4*to] = v;
    }
  }
}

// ---------------------------------------------------------------- knn + attention + BN1
// Two-sweep MFMA coarse selection: no per-thread key array (the round-1 kk[64]
// spilled to scratch: ~300 MB of FETCH/WRITE). Sweep 1 keeps only running
// per-lane maxes (4 regs), sweep 2 recomputes and compacts candidates >= Tm
// via rare LDS atomics. Quantization chain is monotone + identical in both
// sweeps, so the validated 72-bin-margin exactness argument carries over.
__global__ __launch_bounds__(512, 4) void knn_attn_kernel(
    const float* __restrict__ sq,
    const float* __restrict__ Qm, const float* __restrict__ PKm, const float* __restrict__ PVm,
    const float* __restrict__ featT, const unsigned short* __restrict__ xh,
    float* __restrict__ t1, float* __restrict__ bn1s, float* __restrict__ bn1q)
{
  __shared__ __align__(16) unsigned char smem[35200];
  float* fnS  = (float*)smem;                       // [16][64]
  float* qvS  = (float*)(smem + 4096);              // [16][64]
  float* pknS = (float*)(smem + 8192);              // [16][64]
  float* pvnS = (float*)(smem + 12288);             // [16][64]
  unsigned short* qpm = (unsigned short*)(smem + 16384); // [16][128] partial maxes
  int*   candI  = (int*)(smem + 16384);             // [16][64] (alias qpm, post-threshold)
  float* enS    = (float*)(smem + 20480);           // [16][128]
  int*   outIdx = (int*)(smem + 28672);             // [16][32]
  float* red1   = (float*)(smem + 30720);           // [512]
  float* red2   = (float*)(smem + 32768);           // [512]
  float* sqnS   = (float*)(smem + 34816);           // [16]
  float* thrF   = (float*)(smem + 34880);           // [16] margin threshold (float)
  float* thrFB  = (float*)(smem + 34944);           // [16] fallback threshold (float)
  int*   cnt    = (int*)(smem + 35008);             // [16]
  int*   cntF   = (int*)(smem + 35072);             // [16]
  int*   ovf    = (int*)(smem + 35136);             // [1]

  const int tid  = threadIdx.x;
  const int lane = tid & 63;
  const int w    = tid >> 6;
  const int blk  = blockIdx.x;
  const int b    = blk & 7;                   // XCD-locality swizzle
  const int n0   = (blk >> 3) << 4;           // 16 queries
  const size_t b4096 = (size_t)b << 12;
  const int qa = w, qb = w + 8;               // wave w owns queries w and w+8

  // stage query-side rows + defensive outIdx prefill (valid indices)
  #pragma unroll
  for (int rr=0; rr<2; ++rr){
    int idx = tid + (rr<<9);
    int j = idx>>6, c = idx&63;
    size_t ro = (b4096 + n0 + j)*64 + c;
    fnS[idx]  = featT[ro];
    qvS[idx]  = Qm[ro];
    pknS[idx] = PKm[ro];
    pvnS[idx] = PVm[ro];
  }
  if (tid < 16) sqnS[tid] = sq[b4096 + n0 + tid];
  outIdx[tid & 511] = n0 + (tid>>5);
  __syncthreads();

  const unsigned short* xhb = xh + (b4096 << 6);
  const float* sqb = sq + b4096;
  const int l15  = lane & 15;
  const int acol = (lane >> 4) << 3;   // K-block base
  const int qrow = (lane >> 4) << 2;   // query-row base of acc[r]
  bf16x8 a0 = *(const bf16x8*)&xhb[(size_t)(n0 + l15)*64 + acol];
  bf16x8 a1 = *(const bf16x8*)&xhb[(size_t)(n0 + l15)*64 + acol + 32];
  float sqn_r[4];
  #pragma unroll
  for (int r=0;r<4;++r) sqn_r[r] = sqnS[qrow + r];

  // ---- sweep 1: distances -> per-lane running maxes only
  {
    float emax[4] = {-3e38f,-3e38f,-3e38f,-3e38f};
    #pragma unroll 2
    for (int ch=0; ch<8; ++ch){
      #pragma unroll
      for (int t=0;t<4;++t){
        const int brow = (w<<9) + (ch<<6) + (t<<4) + l15;
        bf16x8 b0 = *(const bf16x8*)&xhb[(size_t)brow*64 + acol];
        bf16x8 b1 = *(const bf16x8*)&xhb[(size_t)brow*64 + acol + 32];
        f32x4 acc = {0.f,0.f,0.f,0.f};
        acc = __builtin_amdgcn_mfma_f32_16x16x32_bf16(a0, b0, acc, 0, 0, 0);
        acc = __builtin_amdgcn_mfma_f32_16x16x32_bf16(a1, b1, acc, 0, 0, 0);
        float sm = sqb[brow];
        #pragma unroll
        for (int r=0;r<4;++r) emax[r] = fmaxf(emax[r], fmaf(2.f, acc[r], -sm));
      }
    }
    #pragma unroll
    for (int r=0;r<4;++r){
      float kf = fmaf(emax[r] - sqn_r[r], 204.8f, 65536.f);
      int k16 = (int)kf; k16 = k16 < 0 ? 0 : (k16 > 65535 ? 65535 : k16);
      qpm[(qrow+r)*128 + (w<<4) + l15] = (unsigned short)k16;
    }
  }
  __syncthreads();

  // ---- per-query threshold via lane-max ballot bit-search (granularity: 64 keys/lane)
  #pragma unroll
  for (int pass=0; pass<2; ++pass){
    const int q = pass ? qb : qa;
    unsigned mA = qpm[q*128 + lane];
    unsigned mB = qpm[q*128 + 64 + lane];
    unsigned lmax = mA > mB ? mA : mB;
    unsigned T = 0;
    #pragma unroll
    for (int bit=15; bit>=0; --bit){
      unsigned cand = T | (1u<<bit);
      int c2 = (int)__popcll(__ballot(lmax >= cand));
      if (c2 >= 32) T = cand;
    }
    if (lane == 0){
      unsigned Tm  = (T > 72u) ? (T - 72u) : 0u;  // 72 bins = 0.352 (>=7 sigma of bf16 err)
      unsigned Tfb = (T > 2u)  ? (T - 2u)  : 0u;  // fallback: no margin (±2 bin rounding)
      thrF[q]  = (float)Tm;
      thrFB[q] = (float)Tfb;
    }
  }
  if (tid < 16) cnt[tid] = 0;
  if (tid == 0) *ovf = 0;
  __syncthreads();

  // ---- sweep 2: recompute + streamed compaction straight from MFMA layout
  {
    float tf[4];
    #pragma unroll
    for (int r=0;r<4;++r) tf[r] = thrF[qrow + r];
    #pragma unroll 2
    for (int ch=0; ch<8; ++ch){
      #pragma unroll
      for (int t=0;t<4;++t){
        const int brow = (w<<9) + (ch<<6) + (t<<4) + l15;
        bf16x8 b0 = *(const bf16x8*)&xhb[(size_t)brow*64 + acol];
        bf16x8 b1 = *(const bf16x8*)&xhb[(size_t)brow*64 + acol + 32];
        f32x4 acc = {0.f,0.f,0.f,0.f};
        acc = __builtin_amdgcn_mfma_f32_16x16x32_bf16(a0, b0, acc, 0, 0, 0);
        acc = __builtin_amdgcn_mfma_f32_16x16x32_bf16(a1, b1, acc, 0, 0, 0);
        float sm = sqb[brow];
        #pragma unroll
        for (int r=0;r<4;++r){
          float kf = fmaf(fmaf(2.f, acc[r], -sm) - sqn_r[r], 204.8f, 65536.f);
          if (kf >= tf[r]){
            int slot = atomicAdd(&cnt[qrow+r], 1);
            if (slot < 64) candI[(qrow+r)*64 + slot] = brow;
            else *ovf = 1;
          }
        }
      }
    }
  }
  __syncthreads();

  // ---- rare fallback: some query overflowed 64 candidates -> redo w/o margin
  if (*ovf){
    int   fl[4]; float tfb[4];
    #pragma unroll
    for (int r=0;r<4;++r){ fl[r] = cnt[qrow+r] > 64; tfb[r] = thrFB[qrow+r]; }
    if (tid < 16) cntF[tid] = 0;
    __syncthreads();
    #pragma unroll 2
    for (int ch=0; ch<8; ++ch){
      #pragma unroll
      for (int t=0;t<4;++t){
        const int brow = (w<<9) + (ch<<6) + (t<<4) + l15;
        bf16x8 b0 = *(const bf16x8*)&xhb[(size_t)brow*64 + acol];
        bf16x8 b1 = *(const bf16x8*)&xhb[(size_t)brow*64 + acol + 32];
        f32x4 acc = {0.f,0.f,0.f,0.f};
        acc = __builtin_amdgcn_mfma_f32_16x16x32_bf16(a0, b0, acc, 0, 0, 0);
        acc = __builtin_amdgcn_mfma_f32_16x16x32_bf16(a1, b1, acc, 0, 0, 0);
        float sm = sqb[brow];
        #pragma unroll
        for (int r=0;r<4;++r){
          float kf = fmaf(fmaf(2.f, acc[r], -sm) - sqn_r[r], 204.8f, 65536.f);
          if (fl[r] && kf >= tfb[r]){
            int slot = atomicAdd(&cntF[qrow+r], 1);
            if (slot < 64) candI[(qrow+r)*64 + slot] = brow;
          }
        }
      }
    }
    __syncthreads();
  }

  // ---- exact fp32 refine + 64-lane bitonic -> exact top-32 per query
  const unsigned long long below = (1ull<<lane) - 1ull;
  (void)below;
  #pragma unroll
  for (int pass=0; pass<2; ++pass){
    const int q = pass ? qb : qa;
    int cq = cnt[q];
    int sQ = (cq > 64) ? cntF[q] : cq;
    if (sQ > 64) sQ = 64;
    int mj = -1; unsigned keyE = 0u;
    if (lane < sQ){
      mj = candI[q*64 + lane];
      const float* fm = featT + (b4096 + mj)*64;
      const float* fq = fnS + (q<<6);
      float as = 0.f;
      #pragma unroll
      for (int d4=0; d4<16; ++d4){
        float4 qv = *(const float4*)&fq[d4<<2];
        float4 mv = *(const float4*)&fm[d4<<2];
        as = fmaf(qv.x, mv.x, as); as = fmaf(qv.y, mv.y, as);
        as = fmaf(qv.z, mv.z, as); as = fmaf(qv.w, mv.w, as);
      }
      float de = (2.f*as - sqnS[q]) - sq[b4096 + mj];
      keyE = keyOf(de);
    }
    unsigned long long C = ((unsigned long long)keyE << 32) |
                           (unsigned long long)(~(unsigned)mj);
    #pragma unroll
    for (int k2=2; k2<=64; k2<<=1){
      #pragma unroll
      for (int j2=k2>>1; j2>=1; j2>>=1){
        unsigned long long P = (unsigned long long)__shfl_xor((long long)C, j2, 64);
        bool lowIdx  = ((lane & j2) == 0);
        bool keepMax = (lowIdx == ((lane & k2) == 0));
        unsigned long long mx = C > P ? C : P;
        unsigned long long mn = C > P ? P : C;
        C = keepMax ? mx : mn;
      }
    }
    if (lane < 32) outIdx[(q<<5)+lane] = (int)(~(unsigned)(C & 0xFFFFFFFFull)) & (Ndim-1);
  }
  __syncthreads();

  // ---- attention energies: 2048 tasks = 16q x 4h x 32k
  #pragma unroll
  for (int p=0;p<4;++p){
    int task = tid + (p<<9);
    int jn = task>>7, h = (task>>5)&3, k2 = task&31;
    int mj = outIdx[(jn<<5)+k2] & (Ndim-1);
    const float4* pk4 = (const float4*)(PKm + (b4096 + mj)*64 + (h<<4));
    const float4* qq4 = (const float4*)&qvS[(jn<<6)+(h<<4)];
    const float4* nn4 = (const float4*)&pknS[(jn<<6)+(h<<4)];
    float e = 0.f;
    #pragma unroll
    for (int d=0;d<4;++d){
      float4 kv = pk4[d], qq = qq4[d], nn = nn4[d];
      e += qq.x*(kv.x-nn.x) + qq.y*(kv.y-nn.y) + qq.z*(kv.z-nn.z) + qq.w*(kv.w-nn.w);
    }
    enS[(jn<<7)+(h<<5)+k2] = e * 0.25f;
  }
  __syncthreads();

  // ---- softmax, wave-parallel: 8 lanes per (q,h), shfl-xor reduce
  {
    int g = tid>>3, l8 = tid&7;           // g in [0,64): 16 jn x 4 h
    int jn = g>>2, h = g&3;
    float* ep = &enS[(jn<<7)+(h<<5)];
    float v0 = ep[l8], v1 = ep[l8+8], v2 = ep[l8+16], v3 = ep[l8+24];
    float mx = fmaxf(fmaxf(v0,v1), fmaxf(v2,v3));
    mx = fmaxf(mx, __shfl_xor(mx, 1, 64));
    mx = fmaxf(mx, __shfl_xor(mx, 2, 64));
    mx = fmaxf(mx, __shfl_xor(mx, 4, 64));
    v0 = __expf(v0-mx); v1 = __expf(v1-mx); v2 = __expf(v2-mx); v3 = __expf(v3-mx);
    float s = v0+v1+v2+v3;
    s += __shfl_xor(s, 1, 64);
    s += __shfl_xor(s, 2, 64);
    s += __shfl_xor(s, 4, 64);
    float inv = 1.f/s;
    ep[l8] = v0*inv; ep[l8+8] = v1*inv; ep[l8+16] = v2*inv; ep[l8+24] = v3*inv;
  }
  __syncthreads();

  // ---- PV gather + residual + t1 write
  float tv[2];
  #pragma unroll
  for (int rr=0; rr<2; ++rr){
    int jn = (tid>>6) + (rr<<3);
    int c = tid&63, h = c>>4;
    float a2 = 0.f;
    #pragma unroll 8
    for (int k2=0;k2<32;++k2){
      int mj = outIdx[(jn<<5)+k2] & (Ndim-1);
      a2 += enS[(jn<<7)+(h<<5)+k2] * (PVm[(b4096 + mj)*64 + c] - pvnS[(jn<<6)+c]);
    }
    tv[rr] = fnS[(jn<<6)+c] + a2;
    t1[(b4096 + n0 + jn)*64 + c] = tv[rr];
  }
  // ---- fused BN1 stats over this WG's 16 rows
  red1[tid] = tv[0] + tv[1];
  red2[tid] = tv[0]*tv[0] + tv[1]*tv[1];
  __syncthreads();
  if (tid < 64){
    float S = 0.f, S2 = 0.f;
    #pragma unroll
    for (int j=0;j<8;++j){ S += red1[(j<<6)+tid]; S2 += red2[(j<<6)+tid]; }
    atomicAdd(&bn1s[tid], S);
    atomicAdd(&bn1q[tid], S2);
  }
}

// ---------------------------------------------------------------- MLP + BN2 stats
__global__ __launch_bounds__(256) void mlp_kernel(const float* __restrict__ t1,
    const float* __restrict__ w1, const float* __restrict__ w2,
    const float* __restrict__ g1, const float* __restrict__ b1,
    const float* __restrict__ bns, const float* __restrict__ bnq,
    float* __restrict__ t2, float* __restrict__ bn2s, float* __restrict__ bn2q)
{
  __shared__ __align__(16) float f1l[64*68];
  __shared__ __align__(16) float hl[64*68];
  __shared__ __align__(16) float w1s[64*64];
  __shared__ __align__(16) float w2s[64*64];
  __shared__ float mu[64], rs[64], gg[64], bb[64];
  const int tid = threadIdx.x;
  if (tid < 64){
    float m = bns[tid] * (1.f/32768.f);
    float v = bnq[tid] * (1.f/32768.f) - m*m;
    mu[tid] = m; rs[tid] = 1.f/sqrtf(v + BN_EPS);
    gg[tid] = g1[tid]; bb[tid] = b1[tid];
  }
  __syncthreads();
  const size_t rowBase = (size_t)blockIdx.x*64;
  for (int k=0;k<16;++k){
    int idx = tid + (k<<8);
    int r = idx>>6, c = idx&63;
    float v = t1[(rowBase + r)*64 + c];
    f1l[r*68+c] = (v - mu[c])*rs[c]*gg[c] + bb[c];
  }
  const int tr = tid>>4, to = tid&15;
  float ff[4][4];
  #pragma unroll
  for (int r=0;r<4;++r){ ff[r][0]=0.f; ff[r][1]=0.f; ff[r][2]=0.f; ff[r][3]=0.f; }

  for (int hc=0; hc<4; ++hc){
    __syncthreads();
    for (int k=0;k<16;++k){
      int idx = tid + (k<<8);
      int o = idx>>6, c = idx&63;
      w1s[wofs(o, c>>2) + (c&3)] = w1[(size_t)(hc*64+o)*64 + c];
      w2s[wofs(o, c>>2) + (c&3)] = w2[(size_t)o*256 + hc*64 + c];
    }
    __syncthreads();
    float hv[4][4];
    #pragma unroll
    for (int r=0;r<4;++r){ hv[r][0]=0.f; hv[r][1]=0.f; hv[r][2]=0.f; hv[r][3]=0.f; }
    #pragma unroll 4
    for (int c4=0;c4<16;++c4){
      float4 f[4], w[4];
      #pragma unroll
      for (int r=0;r<4;++r)  f[r] = *(const float4*)&f1l[(4*tr+r)*68 + (c4<<2)];
      #pragma unroll
      for (int oo=0;oo<4;++oo) w[oo] = *(const float4*)&w1s[wofs(4*to+oo, c4)];
      #pragma unroll
      for (int r=0;r<4;++r)
        #pragma unroll
        for (int oo=0;oo<4;++oo)
          hv[r][oo] += dot4(f[r], w[oo]);
    }
    #pragma unroll
    for (int r=0;r<4;++r){
      float4 v;
      float x0=hv[r][0], x1=hv[r][1], x2=hv[r][2], x3=hv[r][3];
      v.x = (x0>0.f)?x0:0.2f*x0; v.y = (x1>0.f)?x1:0.2f*x1;
      v.z = (x2>0.f)?x2:0.2f*x2; v.w = (x3>0.f)?x3:0.2f*x3;
      *(float4*)&hl[(4*tr+r)*68 + 4*to] = v;
    }
    __syncthreads();
    #pragma unroll 4
    for (int o4=0;o4<16;++o4){
      float4 h[4], w[4];
      #pragma unroll
      for (int r=0;r<4;++r)  h[r] = *(const float4*)&hl[(4*tr+r)*68 + (o4<<2)];
      #pragma unroll
      for (int oo=0;oo<4;++oo) w[oo] = *(const float4*)&w2s[wofs(4*to+oo, o4)];
      #pragma unroll
      for (int r=0;r<4;++r)
        #pragma unroll
        for (int oo=0;oo<4;++oo)
          ff[r][oo] += dot4(h[r], w[oo]);
    }
  }
  float ls[4]  = {0.f,0.f,0.f,0.f};
  float ls2[4] = {0.f,0.f,0.f,0.f};
  #pragma unroll
  for (int r=0;r<4;++r){
    float4 v;
    v.x = f1l[(4*tr+r)*68 + 4*to+0] + ff[r][0];
    v.y = f1l[(4*tr+r)*68 + 4*to+1] + ff[r][1];
    v.z = f1l[(4*tr+r)*68 + 4*to+2] + ff[r][2];
    v.w = f1l[(4*tr+r)*68 + 4*to+3] + ff[r][3];
    *(float4*)&t2[(rowBase + 4*tr + r)*64 + 4*to] = v;
    ls[0]+=v.x; ls[1]+=v.y; ls[2]+=v.z; ls[3]+=v.w;
    ls2[0]+=v.x*v.x; ls2[1]+=v.y*v.y; ls2[2]+=v.z*v.z; ls2[3]+=v.w*v.w;
  }
  __syncthreads();
  #pragma unroll
  for (int i=0;i<4;++i){
    hl[tr*64 + 4*to + i]        = ls[i];
    hl[1024 + tr*64 + 4*to + i] = ls2[i];
  }
  __syncthreads();
  if (tid < 64){
    float S = 0.f, S2 = 0.f;
    #pragma unroll
    for (int g2=0; g2<16; ++g2){ S += hl[g2*64 + tid]; S2 += hl[1024 + g2*64 + tid]; }
    atomicAdd(&bn2s[tid], S);
    atomicAdd(&bn2q[tid], S2);
  }
}

// ---------------------------------------------------------------- final BN2 + transpose
__global__ __launch_bounds__(256) void final_kernel(const float* __restrict__ t2,
    const float* __restrict__ bns, const float* __restrict__ bnq,
    const float* __restrict__ g2, const float* __restrict__ b2,
    float* __restrict__ out)
{
  __shared__ float tile[64*65];
  __shared__ float mu[64], rs[64], gg[64], bb[64];
  const int tid = threadIdx.x;
  const int b = blockIdx.y;
  const int n0 = blockIdx.x*64;
  if (tid < 64){
    float m = bns[tid] * (1.f/32768.f);
    float v = bnq[tid] * (1.f/32768.f) - m*m;
    mu[tid] = m; rs[tid] = 1.f/sqrtf(v + BN_EPS);
    gg[tid] = g2[tid]; bb[tid] = b2[tid];
  }
  __syncthreads();
  for (int k=0;k<16;++k){
    int idx = tid + (k<<8);
    int r = idx>>6, c = idx&63;
    float v = t2[((size_t)b*Ndim + n0 + r)*64 + c];
    tile[r*65+c] = (v - mu[c])*rs[c]*gg[c] + bb[c];
  }
  __syncthreads();
  for (int k=0;k<16;++k){
    int idx = tid + (k<<8);
    int c = idx>>6, nn = idx&63;
    out[((size_t)b*64 + c)*Ndim + n0 + nn] = tile[nn*65+c];
  }
}

extern "C" void kernel_launch(void* const* d_in, const int* in_sizes, int n_in,
                              void* d_out, int out_size, void* d_ws, size_t ws_size,
                              hipStream_t stream)
{
  (void)in_sizes; (void)n_in; (void)out_size; (void)ws_size;
  const float* x  = (const float*)d_in[0];
  const float* wq = (const float*)d_in[1];
  const float* wk = (const float*)d_in[2];
  const float* wv = (const float*)d_in[3];
  const float* w1 = (const float*)d_in[4];
  const float* w2 = (const float*)d_in[5];
  const float* g1 = (const float*)d_in[6];
  const float* b1 = (const float*)d_in[7];
  const float* g2 = (const float*)d_in[8];
  const float* b2 = (const float*)d_in[9];
  float* out = (float*)d_out;

  const size_t NE = (size_t)ROWS*64;
  float* sq   = (float*)d_ws;
  float* Qb   = sq + ROWS;
  float* PKb  = Qb + NE;
  float* PVb  = PKb + NE;
  float* t1   = PVb + NE;
  float* t2   = t1 + NE;            // doubles as featT until mlp overwrites it
  float* acc  = t2 + NE;            // 256 floats: bn1sum, bn1sq, bn2sum, bn2sq
  unsigned short* xh = (unsigned short*)(acc + 256);   // NE bf16 = 4 MB

  prep_proj_kernel<<<dim3(512), 256, 0, stream>>>(x, wq, wk, wv, sq, Qb, PKb, PVb, acc, t2, xh);
  knn_attn_kernel<<<dim3(2048), 512, 0, stream>>>(sq, Qb, PKb, PVb, t2, xh, t1, acc, acc+64);
  mlp_kernel<<<dim3(512), 256, 0, stream>>>(t1, w1, w2, g1, b1, acc, acc+64, t2, acc+128, acc+192);
  final_kernel<<<dim3(64,8), 256, 0, stream>>>(t2, acc+128, acc+192, g2, b2, out);
}

// Round 4
// 376.609 us; speedup vs baseline: 1.3459x; 1.3459x over previous
//
#include <hip/hip_runtime.h>

#define Bdim 8
#define Cdim 64
#define Ndim 4096
#define Kdim 32
#define ROWS (Bdim*Ndim)   /* 32768 */
#define BN_EPS 1e-5f

using f32x4  = __attribute__((ext_vector_type(4))) float;
using f16x8  = __attribute__((ext_vector_type(8))) _Float16;

__device__ __forceinline__ float dot4(float4 a, float4 b){
  return a.x*b.x + a.y*b.y + a.z*b.z + a.w*b.w;
}
__device__ __forceinline__ int wofs(int o, int g){ return o*64 + (((g ^ ((o>>2)&7)))<<2); }
__device__ __forceinline__ unsigned keyOf(float f){
  unsigned u = __float_as_uint(f);
  return (u & 0x80000000u) ? ~u : (u ^ 0x80000000u);
}

// ---------------------------------------------------------------- prep+proj fused
__global__ __launch_bounds__(256) void prep_proj_kernel(const float* __restrict__ x,
    const float* __restrict__ wq, const float* __restrict__ wk,
    const float* __restrict__ wv,
    float* __restrict__ sq,
    float* __restrict__ Qo, float* __restrict__ PKo, float* __restrict__ PVo,
    float* __restrict__ accZ,
    float* __restrict__ featT, unsigned short* __restrict__ xh)
{
  __shared__ __align__(16) float ftile[64*68];
  __shared__ __align__(16) float Ws[3][64*64];
  const int tid = threadIdx.x;
  const int blk = blockIdx.x;
  const int b  = blk & 7;
  const int n0 = (blk >> 3) * 64;
  const size_t rowBase = (size_t)b*Ndim + n0;
  if (blk == 0) accZ[tid] = 0.f;   // 256 floats: bn1s, bn1q, bn2s, bn2q
  for (int k=0;k<16;++k){
    int idx = tid + (k<<8);
    int c = idx>>6, nn = idx&63;
    ftile[nn*68+c] = x[((size_t)b*64+c)*Ndim + n0 + nn];
  }
  {
    const float* wp[3] = {wq, wk, wv};
    for (int m=0;m<3;++m)
      for (int k=0;k<16;++k){
        int idx = tid + (k<<8);
        int o = idx>>6, c = idx&63;
        Ws[m][wofs(o, c>>2) + (c&3)] = wp[m][o*64 + c];
      }
  }
  __syncthreads();
  // featT (fp32) + xh (fp16 RTNE via native _Float16 cast) writes, coalesced
  for (int k=0;k<16;++k){
    int idx = tid + (k<<8);
    int r = idx>>6, c = idx&63;
    float v = ftile[r*68+c];
    size_t o = (rowBase + r)*64 + c;
    featT[o] = v;
    _Float16 hh = (_Float16)v;
    xh[o] = *reinterpret_cast<unsigned short*>(&hh);
  }
  if (tid < 64){
    float a = 0.f;
    #pragma unroll
    for (int c=0;c<64;++c){ float v = ftile[tid*68+c]; a += v*v; }
    sq[b*Ndim + n0 + tid] = a;
  }
  const int tr = tid>>4, to = tid&15;
  float* outp[3] = {Qo, PKo, PVo};
  for (int m=0;m<3;++m){
    float acc[4][4];
    #pragma unroll
    for (int r=0;r<4;++r){ acc[r][0]=0.f; acc[r][1]=0.f; acc[r][2]=0.f; acc[r][3]=0.f; }
    #pragma unroll 4
    for (int c4=0;c4<16;++c4){
      float4 f[4], w[4];
      #pragma unroll
      for (int r=0;r<4;++r)  f[r] = *(const float4*)&ftile[(4*tr+r)*68 + (c4<<2)];
      #pragma unroll
      for (int oo=0;oo<4;++oo) w[oo] = *(const float4*)&Ws[m][wofs(4*to+oo, c4)];
      #pragma unroll
      for (int r=0;r<4;++r)
        #pragma unroll
        for (int oo=0;oo<4;++oo)
          acc[r][oo] += dot4(f[r], w[oo]);
    }
    #pragma unroll
    for (int r=0;r<4;++r){
      float4 v; v.x=acc[r][0]; v.y=acc[r][1]; v.z=acc[r][2]; v.w=acc[r][3];
      *(float4*)&outp[m][(rowBase + 4*tr + r)*64 + 4*to] = v;
    }
  }
}

// ---------------------------------------------------------------- knn + attention + BN1
// 1024 threads = 16 waves = 16 queries; wave w owns query w.
// ONE fp16-MFMA sweep (16 chunks x 256 keys). Per chunk, each wave's 16x16
// distance tile goes to a small dbuf; redistribution gives each wave its own
// query's 256 keys (4 u16/lane) -> kk[32] u32 regs (64 keys/lane packed).
// Selection fully wave-parallel: ballot threshold on 32-key-group maxima,
// ballot compaction with 16-bin margin (fp16 err 2eps ~ 10 bins), wave-local
// register fallback at T (no re-sweep, no atomics). Exact fp32 refine +
// 64-lane bitonic -> exact top-32.
__global__ __launch_bounds__(1024) void knn_attn_kernel(
    const float* __restrict__ sq,
    const float* __restrict__ Qm, const float* __restrict__ PKm, const float* __restrict__ PVm,
    const float* __restrict__ featT, const unsigned short* __restrict__ xh,
    float* __restrict__ t1, float* __restrict__ bn1s, float* __restrict__ bn1q)
{
  __shared__ __align__(16) unsigned char smem[43200];
  float* fnS  = (float*)smem;                        // [16][64] 4 KB
  float* qvS  = (float*)(smem + 4096);               // [16][64]
  float* pknS = (float*)(smem + 8192);               // [16][64]
  float* pvnS = (float*)(smem + 12288);              // [16][64]
  unsigned short* dbuf = (unsigned short*)(smem + 16384); // 2 x [16][258] u16 = 16512 B
  int*   candI  = (int*)(smem + 16384);              // [16][64] (alias dbuf, post-sweep)
  float* red1   = (float*)(smem + 20480);            // [1024]   (alias dbuf, post-sweep)
  float* red2   = (float*)(smem + 24576);            // [1024]
  float* enS    = (float*)(smem + 32896);            // [16][128] 8 KB
  int*   outIdx = (int*)(smem + 41088);              // [16][32] 2 KB
  float* sqnS   = (float*)(smem + 43136);            // [16]

  const int tid  = threadIdx.x;
  const int lane = tid & 63;
  const int w    = tid >> 6;                  // wave id == owned query
  const int blk  = blockIdx.x;
  const int b    = blk & 7;                   // XCD-locality swizzle
  const int n0   = (blk >> 3) << 4;           // 16 queries
  const size_t b4096 = (size_t)b << 12;

  // ---- stage query-side rows; prefill outIdx with valid indices
  {
    int j = tid>>6, c = tid&63;
    size_t ro = (b4096 + n0 + j)*64 + c;
    fnS[tid]  = featT[ro];
    qvS[tid]  = Qm[ro];
    pknS[tid] = PKm[ro];
    pvnS[tid] = PVm[ro];
    if (tid < 16) sqnS[tid] = sq[b4096 + n0 + tid];
    if (tid < 512) outIdx[tid] = n0 + (tid>>5);
  }
  __syncthreads();

  const unsigned short* xhb = xh + (b4096 << 6);
  const float* sqb = sq + b4096;
  const int l15  = lane & 15;
  const int acol = (lane >> 4) << 3;   // K-block base (8 halves)
  const int qrow = (lane >> 4) << 2;   // query-row base of acc[r]

  unsigned kk[32];   // 64 keys of query w, 2 packed u16 per reg

  { // ---- single sweep: 16 chunks x 256 keys
    f16x8 a0 = *(const f16x8*)&xhb[(size_t)(n0 + l15)*64 + acol];
    f16x8 a1 = *(const f16x8*)&xhb[(size_t)(n0 + l15)*64 + acol + 32];
    #pragma unroll
    for (int ch=0; ch<16; ++ch){
      unsigned short* bw = dbuf + (ch&1)*(16*258);
      const int brow = (ch<<8) + (w<<4) + l15;
      f16x8 b0 = *(const f16x8*)&xhb[(size_t)brow*64 + acol];
      f16x8 b1 = *(const f16x8*)&xhb[(size_t)brow*64 + acol + 32];
      f32x4 acc = {0.f,0.f,0.f,0.f};
      acc = __builtin_amdgcn_mfma_f32_16x16x32_f16(a0, b0, acc, 0, 0, 0);
      acc = __builtin_amdgcn_mfma_f32_16x16x32_f16(a1, b1, acc, 0, 0, 0);
      float sm = sqb[brow];
      #pragma unroll
      for (int r=0;r<4;++r){
        // per-query-constant sqn dropped: ranking within a query unchanged
        float v = fmaf(2.f, acc[r], -sm);            // in (-300, +130)
        int k16 = (int)fmaf(v, 128.f, 40960.f);
        k16 = k16 < 0 ? 0 : (k16 > 65535 ? 65535 : k16);
        bw[(qrow+r)*258 + (w<<4) + l15] = (unsigned short)k16;
      }
      __syncthreads();
      // redistribution: wave w takes its own query's 256 keys (4/lane)
      unsigned k01 = *(const unsigned*)&bw[w*258 + (lane<<2)];
      unsigned k23 = *(const unsigned*)&bw[w*258 + (lane<<2) + 2];
      kk[(ch<<1)]   = k01;
      kk[(ch<<1)+1] = k23;
    }
  }

  // ---- wave-parallel selection for query w (no barriers, no atomics)
  const unsigned long long below = (1ull<<lane) - 1ull;
  int sQ;
  {
    // 32-key-group maxima: mE over kk[0..15] (keys j<32), mO over kk[16..31]
    unsigned mE = 0, mO = 0;
    #pragma unroll
    for (int i=0;i<16;++i){
      unsigned u = kk[i];
      unsigned hv = u >> 16, lv = u & 0xFFFFu;
      unsigned m = hv > lv ? hv : lv;
      mE = mE > m ? mE : m;
    }
    #pragma unroll
    for (int i=16;i<32;++i){
      unsigned u = kk[i];
      unsigned hv = u >> 16, lv = u & 0xFFFFu;
      unsigned m = hv > lv ? hv : lv;
      mO = mO > m ? mO : m;
    }
    unsigned T = 0;
    #pragma unroll
    for (int bit=15; bit>=0; --bit){
      unsigned cand = T | (1u<<bit);
      int c2 = (int)__popcll(__ballot(mE >= cand)) + (int)__popcll(__ballot(mO >= cand));
      if (c2 >= 32) T = cand;
    }
    const unsigned Tm = (T > 16u) ? (T - 16u) : 0u;   // margin 16 bins = 0.125 (fp16 2eps ~ 10)
    int base = 0;
    #pragma unroll
    for (int j=0;j<64;++j){
      unsigned word = kk[((j>>2)<<1) | ((j>>1)&1)];
      unsigned key  = (j&1) ? (word>>16) : (word & 0xFFFFu);
      bool isc = (key >= Tm);
      unsigned long long mk = __ballot(isc);
      if (isc){
        int slot = base + (int)__popcll(mk & below);
        if (slot < 64) candI[(w<<6)+slot] = ((j>>2)<<8) + (lane<<2) + (j&3);
      }
      base += (int)__popcll(mk);
    }
    if (base > 64){
      // rare wave-local fallback: no margin (count(>=T) >= 32 guaranteed)
      base = 0;
      #pragma unroll
      for (int j=0;j<64;++j){
        unsigned word = kk[((j>>2)<<1) | ((j>>1)&1)];
        unsigned key  = (j&1) ? (word>>16) : (word & 0xFFFFu);
        bool isc = (key >= T);
        unsigned long long mk = __ballot(isc);
        if (isc){
          int slot = base + (int)__popcll(mk & below);
          if (slot < 64) candI[(w<<6)+slot] = ((j>>2)<<8) + (lane<<2) + (j&3);
        }
        base += (int)__popcll(mk);
      }
    }
    sQ = base < 64 ? base : 64;
  }

  // ---- exact fp32 refine + 64-lane bitonic -> exact top-32
  {
    int mj = -1; unsigned keyE = 0u;
    if (lane < sQ){
      mj = candI[(w<<6)+lane];
      const float* fm = featT + (b4096 + mj)*64;
      const float* fq = fnS + (w<<6);
      float as = 0.f;
      #pragma unroll 4
      for (int d4=0; d4<16; ++d4){
        float4 qv = *(const float4*)&fq[d4<<2];
        float4 mv = *(const float4*)&fm[d4<<2];
        as = fmaf(qv.x, mv.x, as); as = fmaf(qv.y, mv.y, as);
        as = fmaf(qv.z, mv.z, as); as = fmaf(qv.w, mv.w, as);
      }
      float de = (2.f*as - sqnS[w]) - sq[b4096 + mj];
      keyE = keyOf(de);
    }
    unsigned long long C = ((unsigned long long)keyE << 32) |
                           (unsigned long long)(~(unsigned)mj);
    #pragma unroll
    for (int k2=2; k2<=64; k2<<=1){
      #pragma unroll
      for (int j2=k2>>1; j2>=1; j2>>=1){
        unsigned long long P = (unsigned long long)__shfl_xor((long long)C, j2, 64);
        bool lowIdx  = ((lane & j2) == 0);
        bool keepMax = (lowIdx == ((lane & k2) == 0));
        unsigned long long mx = C > P ? C : P;
        unsigned long long mn = C > P ? P : C;
        C = keepMax ? mx : mn;
      }
    }
    if (lane < 32) outIdx[(w<<5)+lane] = (int)(~(unsigned)(C & 0xFFFFFFFFull)) & (Ndim-1);
  }
  __syncthreads();

  // ---- attention energies: 2048 tasks = 16q x 4h x 32k, 2 per thread
  #pragma unroll
  for (int p=0;p<2;++p){
    int task = tid + (p<<10);
    int jn = task>>7, h = (task>>5)&3, k2 = task&31;
    int mj = outIdx[(jn<<5)+k2] & (Ndim-1);
    const float4* pk4 = (const float4*)(PKm + (b4096 + mj)*64 + (h<<4));
    const float4* qq4 = (const float4*)&qvS[(jn<<6)+(h<<4)];
    const float4* nn4 = (const float4*)&pknS[(jn<<6)+(h<<4)];
    float e = 0.f;
    #pragma unroll
    for (int d=0;d<4;++d){
      float4 kv = pk4[d], qq = qq4[d], nn = nn4[d];
      e += qq.x*(kv.x-nn.x) + qq.y*(kv.y-nn.y) + qq.z*(kv.z-nn.z) + qq.w*(kv.w-nn.w);
    }
    enS[(jn<<7)+(h<<5)+k2] = e * 0.25f;
  }
  __syncthreads();

  // ---- softmax, wave-parallel: 16 lanes per (q,h)
  {
    int g = tid>>4, l16 = tid&15;         // 64 groups = 16 jn x 4 h
    int jn = g>>2, h = g&3;
    float* ep = &enS[(jn<<7)+(h<<5)];
    float v0 = ep[l16], v1 = ep[l16+16];
    float mx = fmaxf(v0, v1);
    mx = fmaxf(mx, __shfl_xor(mx, 1, 64));
    mx = fmaxf(mx, __shfl_xor(mx, 2, 64));
    mx = fmaxf(mx, __shfl_xor(mx, 4, 64));
    mx = fmaxf(mx, __shfl_xor(mx, 8, 64));
    v0 = expf(v0-mx); v1 = expf(v1-mx);
    float s = v0+v1;
    s += __shfl_xor(s, 1, 64);
    s += __shfl_xor(s, 2, 64);
    s += __shfl_xor(s, 4, 64);
    s += __shfl_xor(s, 8, 64);
    float inv = 1.f/s;
    ep[l16] = v0*inv; ep[l16+16] = v1*inv;
  }
  __syncthreads();

  // ---- PV gather + residual + t1 write (one row per wave)
  float tv;
  {
    int c = lane, h = c>>4;
    float a2 = 0.f;
    #pragma unroll 4
    for (int k2=0;k2<32;++k2){
      int mj = outIdx[(w<<5)+k2] & (Ndim-1);
      a2 += enS[(w<<7)+(h<<5)+k2] * (PVm[(b4096 + mj)*64 + c] - pvnS[(w<<6)+c]);
    }
    tv = fnS[(w<<6)+c] + a2;
    t1[(b4096 + n0 + w)*64 + c] = tv;
  }
  // ---- fused BN1 stats over this WG's 16 rows
  red1[tid] = tv;
  red2[tid] = tv*tv;
  __syncthreads();
  if (tid < 64){
    float S = 0.f, S2 = 0.f;
    #pragma unroll
    for (int j=0;j<16;++j){ S += red1[(j<<6)+tid]; S2 += red2[(j<<6)+tid]; }
    atomicAdd(&bn1s[tid], S);
    atomicAdd(&bn1q[tid], S2);
  }
}

// ---------------------------------------------------------------- MLP + BN2 stats
__global__ __launch_bounds__(256) void mlp_kernel(const float* __restrict__ t1,
    const float* __restrict__ w1, const float* __restrict__ w2,
    const float* __restrict__ g1, const float* __restrict__ b1,
    const float* __restrict__ bns, const float* __restrict__ bnq,
    float* __restrict__ t2, float* __restrict__ bn2s, float* __restrict__ bn2q)
{
  __shared__ __align__(16) float f1l[64*68];
  __shared__ __align__(16) float hl[64*68];
  __shared__ __align__(16) float w1s[64*64];
  __shared__ __align__(16) float w2s[64*64];
  __shared__ float mu[64], rs[64], gg[64], bb[64];
  const int tid = threadIdx.x;
  if (tid < 64){
    float m = bns[tid] * (1.f/32768.f);
    float v = bnq[tid] * (1.f/32768.f) - m*m;
    mu[tid] = m; rs[tid] = 1.f/sqrtf(v + BN_EPS);
    gg[tid] = g1[tid]; bb[tid] = b1[tid];
  }
  __syncthreads();
  const size_t rowBase = (size_t)blockIdx.x*64;
  for (int k=0;k<16;++k){
    int idx = tid + (k<<8);
    int r = idx>>6, c = idx&63;
    float v = t1[(rowBase + r)*64 + c];
    f1l[r*68+c] = (v - mu[c])*rs[c]*gg[c] + bb[c];
  }
  const int tr = tid>>4, to = tid&15;
  float ff[4][4];
  #pragma unroll
  for (int r=0;r<4;++r){ ff[r][0]=0.f; ff[r][1]=0.f; ff[r][2]=0.f; ff[r][3]=0.f; }

  for (int hc=0; hc<4; ++hc){
    __syncthreads();
    for (int k=0;k<16;++k){
      int idx = tid + (k<<8);
      int o = idx>>6, c = idx&63;
      w1s[wofs(o, c>>2) + (c&3)] = w1[(size_t)(hc*64+o)*64 + c];
      w2s[wofs(o, c>>2) + (c&3)] = w2[(size_t)o*256 + hc*64 + c];
    }
    __syncthreads();
    float hv[4][4];
    #pragma unroll
    for (int r=0;r<4;++r){ hv[r][0]=0.f; hv[r][1]=0.f; hv[r][2]=0.f; hv[r][3]=0.f; }
    #pragma unroll 4
    for (int c4=0;c4<16;++c4){
      float4 f[4], w[4];
      #pragma unroll
      for (int r=0;r<4;++r)  f[r] = *(const float4*)&f1l[(4*tr+r)*68 + (c4<<2)];
      #pragma unroll
      for (int oo=0;oo<4;++oo) w[oo] = *(const float4*)&w1s[wofs(4*to+oo, c4)];
      #pragma unroll
      for (int r=0;r<4;++r)
        #pragma unroll
        for (int oo=0;oo<4;++oo)
          hv[r][oo] += dot4(f[r], w[oo]);
    }
    #pragma unroll
    for (int r=0;r<4;++r){
      float4 v;
      float x0=hv[r][0], x1=hv[r][1], x2=hv[r][2], x3=hv[r][3];
      v.x = (x0>0.f)?x0:0.2f*x0; v.y = (x1>0.f)?x1:0.2f*x1;
      v.z = (x2>0.f)?x2:0.2f*x2; v.w = (x3>0.f)?x3:0.2f*x3;
      *(float4*)&hl[(4*tr+r)*68 + 4*to] = v;
    }
    __syncthreads();
    #pragma unroll 4
    for (int o4=0;o4<16;++o4){
      float4 h[4], w[4];
      #pragma unroll
      for (int r=0;r<4;++r)  h[r] = *(const float4*)&hl[(4*tr+r)*68 + (o4<<2)];
      #pragma unroll
      for (int oo=0;oo<4;++oo) w[oo] = *(const float4*)&w2s[wofs(4*to+oo, o4)];
      #pragma unroll
      for (int r=0;r<4;++r)
        #pragma unroll
        for (int oo=0;oo<4;++oo)
          ff[r][oo] += dot4(h[r], w[oo]);
    }
  }
  float ls[4]  = {0.f,0.f,0.f,0.f};
  float ls2[4] = {0.f,0.f,0.f,0.f};
  #pragma unroll
  for (int r=0;r<4;++r){
    float4 v;
    v.x = f1l[(4*tr+r)*68 + 4*to+0] + ff[r][0];
    v.y = f1l[(4*tr+r)*68 + 4*to+1] + ff[r][1];
    v.z = f1l[(4*tr+r)*68 + 4*to+2] + ff[r][2];
    v.w = f1l[(4*tr+r)*68 + 4*to+3] + ff[r][3];
    *(float4*)&t2[(rowBase + 4*tr + r)*64 + 4*to] = v;
    ls[0]+=v.x; ls[1]+=v.y; ls[2]+=v.z; ls[3]+=v.w;
    ls2[0]+=v.x*v.x; ls2[1]+=v.y*v.y; ls2[2]+=v.z*v.z; ls2[3]+=v.w*v.w;
  }
  __syncthreads();
  #pragma unroll
  for (int i=0;i<4;++i){
    hl[tr*64 + 4*to + i]        = ls[i];
    hl[1024 + tr*64 + 4*to + i] = ls2[i];
  }
  __syncthreads();
  if (tid < 64){
    float S = 0.f, S2 = 0.f;
    #pragma unroll
    for (int g2=0; g2<16; ++g2){ S += hl[g2*64 + tid]; S2 += hl[1024 + g2*64 + tid]; }
    atomicAdd(&bn2s[tid], S);
    atomicAdd(&bn2q[tid], S2);
  }
}

// ---------------------------------------------------------------- final BN2 + transpose
__global__ __launch_bounds__(256) void final_kernel(const float* __restrict__ t2,
    const float* __restrict__ bns, const float* __restrict__ bnq,
    const float* __restrict__ g2, const float* __restrict__ b2,
    float* __restrict__ out)
{
  __shared__ float tile[64*65];
  __shared__ float mu[64], rs[64], gg[64], bb[64];
  const int tid = threadIdx.x;
  const int b = blockIdx.y;
  const int n0 = blockIdx.x*64;
  if (tid < 64){
    float m = bns[tid] * (1.f/32768.f);
    float v = bnq[tid] * (1.f/32768.f) - m*m;
    mu[tid] = m; rs[tid] = 1.f/sqrtf(v + BN_EPS);
    gg[tid] = g2[tid]; bb[tid] = b2[tid];
  }
  __syncthreads();
  for (int k=0;k<16;++k){
    int idx = tid + (k<<8);
    int r = idx>>6, c = idx&63;
    float v = t2[((size_t)b*Ndim + n0 + r)*64 + c];
    tile[r*65+c] = (v - mu[c])*rs[c]*gg[c] + bb[c];
  }
  __syncthreads();
  for (int k=0;k<16;++k){
    int idx = tid + (k<<8);
    int c = idx>>6, nn = idx&63;
    out[((size_t)b*64 + c)*Ndim + n0 + nn] = tile[nn*65+c];
  }
}

extern "C" void kernel_launch(void* const* d_in, const int* in_sizes, int n_in,
                              void* d_out, int out_size, void* d_ws, size_t ws_size,
                              hipStream_t stream)
{
  (void)in_sizes; (void)n_in; (void)out_size; (void)ws_size;
  const float* x  = (const float*)d_in[0];
  const float* wq = (const float*)d_in[1];
  const float* wk = (const float*)d_in[2];
  const float* wv = (const float*)d_in[3];
  const float* w1 = (const float*)d_in[4];
  const float* w2 = (const float*)d_in[5];
  const float* g1 = (const float*)d_in[6];
  const float* b1 = (const float*)d_in[7];
  const float* g2 = (const float*)d_in[8];
  const float* b2 = (const float*)d_in[9];
  float* out = (float*)d_out;

  const size_t NE = (size_t)ROWS*64;
  float* sq   = (float*)d_ws;
  float* Qb   = sq + ROWS;
  float* PKb  = Qb + NE;
  float* PVb  = PKb + NE;
  float* t1   = PVb + NE;
  float* t2   = t1 + NE;            // doubles as featT until mlp overwrites it
  float* acc  = t2 + NE;            // 256 floats: bn1sum, bn1sq, bn2sum, bn2sq
  unsigned short* xh = (unsigned short*)(acc + 256);   // NE fp16 = 4 MB

  prep_proj_kernel<<<dim3(512), 256, 0, stream>>>(x, wq, wk, wv, sq, Qb, PKb, PVb, acc, t2, xh);
  knn_attn_kernel<<<dim3(2048), 1024, 0, stream>>>(sq, Qb, PKb, PVb, t2, xh, t1, acc, acc+64);
  mlp_kernel<<<dim3(512), 256, 0, stream>>>(t1, w1, w2, g1, b1, acc, acc+64, t2, acc+128, acc+192);
  final_kernel<<<dim3(64,8), 256, 0, stream>>>(t2, acc+128, acc+192, g2, b2, out);
}